// Round 9
// baseline (952.036 us; speedup 1.0000x reference)
//
#include <hip/hip_runtime.h>

#define UNITS 512
#define SENSD 256
#define BATCH 256
#define BN (BATCH * UNITS)
#define LOG2E 1.44269504088896340736f
#define CMF (6.0f / 1.001f)   // ODE_UNFOLDS / (ELAPSED_TIME + 0.001)

__device__ __forceinline__ float frcp(float x)  { return __builtin_amdgcn_rcpf(x); }
__device__ __forceinline__ float fexp2(float x) { return __builtin_amdgcn_exp2f(x); }

// async global->LDS DMA, 16B per lane. Global addr is per-lane; LDS dest is
// wave-uniform base, HW writes lane i at base + i*16.
__device__ __forceinline__ void gload16(const float4* g, float4* l) {
  __builtin_amdgcn_global_load_lds(
      (const __attribute__((address_space(1))) unsigned int*)g,
      (__attribute__((address_space(3))) unsigned int*)l, 16, 0, 0);
}

// Fused params: fusedR/fusedS[pq] = {-sigma*log2e, sigma*mu*log2e, w, w*erev}
// cmg[p] = {cm_t, gleak*vleak, cm_t+gleak+eps, 0}
__global__ __launch_bounds__(256) void prep_kernel(
    const float* __restrict__ sigma, const float* __restrict__ mu,
    const float* __restrict__ w, const float* __restrict__ erev,
    const float* __restrict__ ssig, const float* __restrict__ smu,
    const float* __restrict__ sw, const float* __restrict__ serev,
    const float* __restrict__ gleak, const float* __restrict__ vleak,
    const float* __restrict__ cm,
    float4* __restrict__ fusedR, float4* __restrict__ fusedS,
    float4* __restrict__ cmg) {
  int idx = blockIdx.x * 256 + threadIdx.x;
  if (idx < UNITS * UNITS) {
    float s = sigma[idx], m = mu[idx], ww = w[idx], e = erev[idx];
    fusedR[idx] = make_float4(-s * LOG2E, s * m * LOG2E, ww, ww * e);
  } else {
    int j = idx - UNITS * UNITS;
    if (j < SENSD * UNITS) {
      float s = ssig[j], m = smu[j], ww = sw[j], e = serev[j];
      fusedS[j] = make_float4(-s * LOG2E, s * m * LOG2E, ww, ww * e);
    }
  }
  if (idx < UNITS) {
    float cmt = cm[idx] * CMF, gl = gleak[idx];
    cmg[idx] = make_float4(cmt, gl * vleak[idx], cmt + gl + 1e-8f, 0.f);
  }
}

// Sensory partials over 2 d-chunks of 128 (proven r2 structure, unchanged).
__global__ __launch_bounds__(256) void sensory_kernel(
    const float* __restrict__ x, const float* __restrict__ in_w, const float* __restrict__ in_b,
    const float4* __restrict__ fusedS,
    float* __restrict__ snf, float* __restrict__ sdf) {
  __shared__ float xl[8][128];
  int bi = blockIdx.x;
  int phs = bi & 1, qt = (bi >> 1) & 7, bt = bi >> 4;
  int tid = threadIdx.x;
  for (int i = tid; i < 1024; i += 256) {
    int br = i >> 7, dl = i & 127;
    int d = phs * 128 + dl;
    xl[br][dl] = fmaf(x[(bt * 8 + br) * SENSD + d], in_w[d], in_b[d]);
  }
  __syncthreads();
  int ql = tid & 63, bg = tid >> 6;
  int q = qt * 64 + ql;
  int r0 = bg * 2;
  const float4* F = fusedS + (size_t)(phs * 128) * UNITS + q;
  float n0 = 0.f, dn0 = 0.f, n1 = 0.f, dn1 = 0.f;
  #pragma unroll 8
  for (int dd = 0; dd < 128; ++dd) {
    float4 f = F[(size_t)dd * UNITS];
    float v0 = xl[r0][dd], v1 = xl[r0 + 1][dd];
    float t0 = fexp2(fmaf(f.x, v0, f.y));
    float t1 = fexp2(fmaf(f.x, v1, f.y));
    float s0 = frcp(1.0f + t0);
    float s1 = frcp(1.0f + t1);
    n0 = fmaf(f.w, s0, n0);  dn0 = fmaf(f.z, s0, dn0);
    n1 = fmaf(f.w, s1, n1);  dn1 = fmaf(f.z, s1, dn1);
  }
  int bp0 = (bt * 8 + r0) * UNITS + q;
  size_t o = (size_t)phs * BN + bp0;
  snf[o] = n0;         sdf[o] = dn0;
  snf[o + UNITS] = n1; sdf[o + UNITS] = dn1;
}

// One ODE unfold with async-staged F panel.
// grid 1024 x 256 thr: bi = ph + 8*(qt + 8*bt); ph<8 (p-chunk 64), qt<8 (q64),
// bt<16 (btile 16). 4 blocks/CU. F slice (64 rows x 64 lanes x 16B = 64KB) is
// DMA-staged in 8 chunks of 8 rows (8KB), triple-buffered (24KB LDS), with
// counted s_waitcnt vmcnt(2) so 2 chunks stay in flight under compute.
// vmcnt ledger: __syncthreads after prologue drains to 0; 2 DMAs/wave/chunk;
// steady wait vmcnt(2) == "chunk c landed"; tail waits 2 then 0.
__global__ __launch_bounds__(256, 4) void unfold_kernel(
    const float4* __restrict__ fusedR, const float* __restrict__ vprev,
    const float* __restrict__ pn_in, const float* __restrict__ pd_in,  // [8][BN]
    const float* __restrict__ snf, const float* __restrict__ sdf,      // [2][BN]
    const float4* __restrict__ cmg,
    float* __restrict__ vout,
    float* __restrict__ pn_out, float* __restrict__ pd_out,            // [8][BN]
    int first) {
  __shared__ float vl[64][20];        // [p-lane][batch-row], padded
  __shared__ float4 Fl[3][8][64];     // 3 buffers x 8 rows x 64 lanes (24KB)
  int bi = blockIdx.x;
  int ph = bi & 7, qt = (bi >> 3) & 7, bt = bi >> 6;
  int tid = threadIdx.x;
  if (first) {
    for (int i = tid; i < 1024; i += 256) {
      int br = i >> 6, pl = i & 63;
      vl[pl][br] = vprev[(bt * 16 + br) * UNITS + ph * 64 + pl];
    }
  } else {
    for (int i = tid; i < 1024; i += 256) {
      int br = i >> 6, pl = i & 63;
      int p = ph * 64 + pl;
      int bp = (bt * 16 + br) * UNITS + p;
      float num = ((pn_in[bp] + pn_in[BN + bp]) + (pn_in[2 * BN + bp] + pn_in[3 * BN + bp]))
                + ((pn_in[4 * BN + bp] + pn_in[5 * BN + bp]) + (pn_in[6 * BN + bp] + pn_in[7 * BN + bp]))
                + (snf[bp] + snf[BN + bp]);
      float den = ((pd_in[bp] + pd_in[BN + bp]) + (pd_in[2 * BN + bp] + pd_in[3 * BN + bp]))
                + ((pd_in[4 * BN + bp] + pd_in[5 * BN + bp]) + (pd_in[6 * BN + bp] + pd_in[7 * BN + bp]))
                + (sdf[bp] + sdf[BN + bp]);
      float4 c = cmg[p];
      float v = fmaf(c.x, vprev[bp], c.y + num) * frcp(c.z + den);
      vl[pl][br] = v;
      if (qt == 0) vout[bp] = v;
    }
  }
  __syncthreads();   // publishes vl AND drains vmcnt to 0 (DMA ledger baseline)

  int ql = tid & 63, w = tid >> 6;    // w < 4 (wave id); also the batch group
  int q = qt * 64 + ql;
  int r0 = w * 4;
  // per-lane global base of this block's F slice (row stride = UNITS float4s)
  const float4* Fg = fusedR + (size_t)(ph * 64) * UNITS + qt * 64 + ql;
  int rw0 = w * 2, rw1 = rw0 + 1;     // each wave DMAs 2 rows per chunk

  // prologue: issue chunks 0 and 1
  gload16(Fg + (size_t)(0 * 8 + rw0) * UNITS, &Fl[0][rw0][0]);
  gload16(Fg + (size_t)(0 * 8 + rw1) * UNITS, &Fl[0][rw1][0]);
  gload16(Fg + (size_t)(1 * 8 + rw0) * UNITS, &Fl[1][rw0][0]);
  gload16(Fg + (size_t)(1 * 8 + rw1) * UNITS, &Fl[1][rw1][0]);

  float n0 = 0.f, n1 = 0.f, n2 = 0.f, n3 = 0.f;
  float d0 = 0.f, d1 = 0.f, d2 = 0.f, d3 = 0.f;
  #pragma unroll
  for (int c = 0; c < 8; ++c) {
    // wait for chunk c's 2 DMAs (the 2 newest belong to chunk c+1), then
    // barrier so ALL waves' chunk-c rows are visible. Never drain to 0 mid-loop.
    if (c < 7) { asm volatile("s_waitcnt vmcnt(2)" ::: "memory"); }
    else       { asm volatile("s_waitcnt vmcnt(0)" ::: "memory"); }
    __builtin_amdgcn_s_barrier();
    __builtin_amdgcn_sched_barrier(0);   // pin: no LDS read hoisted above this
    if (c < 6) {
      int nb = (c + 2) % 3;   // buffer last read at chunk c-1, all waves past it
      gload16(Fg + (size_t)((c + 2) * 8 + rw0) * UNITS, &Fl[nb][rw0][0]);
      gload16(Fg + (size_t)((c + 2) * 8 + rw1) * UNITS, &Fl[nb][rw1][0]);
    }
    int cur = c % 3;
    #pragma unroll
    for (int rr = 0; rr < 8; ++rr) {
      float4 f = Fl[cur][rr][ql];                      // ds_read_b128, conflict-free
      float4 vv = *(const float4*)&vl[c * 8 + rr][r0]; // wave-broadcast ds_read_b128
      float t0 = fexp2(fmaf(f.x, vv.x, f.y));
      float t1 = fexp2(fmaf(f.x, vv.y, f.y));
      float t2 = fexp2(fmaf(f.x, vv.z, f.y));
      float t3 = fexp2(fmaf(f.x, vv.w, f.y));
      float s0 = frcp(1.0f + t0);
      float s1 = frcp(1.0f + t1);
      float s2 = frcp(1.0f + t2);
      float s3 = frcp(1.0f + t3);
      n0 = fmaf(f.w, s0, n0);  d0 = fmaf(f.z, s0, d0);
      n1 = fmaf(f.w, s1, n1);  d1 = fmaf(f.z, s1, d1);
      n2 = fmaf(f.w, s2, n2);  d2 = fmaf(f.z, s2, d2);
      n3 = fmaf(f.w, s3, n3);  d3 = fmaf(f.z, s3, d3);
    }
  }
  int bp = (bt * 16 + r0) * UNITS + q;
  size_t o = (size_t)ph * BN + bp;
  pn_out[o] = n0;             pd_out[o] = d0;
  pn_out[o + UNITS] = n1;     pd_out[o + UNITS] = d1;
  pn_out[o + 2 * UNITS] = n2; pd_out[o + 2 * UNITS] = d2;
  pn_out[o + 3 * UNITS] = n3; pd_out[o + 3 * UNITS] = d3;
}

// Final combine: v6 from partials_5; write outputs and v_pre.
__global__ __launch_bounds__(256) void final_kernel(
    const float* __restrict__ vprev,
    const float* __restrict__ pn, const float* __restrict__ pd,   // [8][BN]
    const float* __restrict__ snf, const float* __restrict__ sdf, // [2][BN]
    const float4* __restrict__ cmg,
    const float* __restrict__ ow, const float* __restrict__ ob,
    float* __restrict__ out) {
  int idx = blockIdx.x * 256 + threadIdx.x;
  if (idx >= BN) return;
  int p = idx & (UNITS - 1);
  float num = ((pn[idx] + pn[BN + idx]) + (pn[2 * BN + idx] + pn[3 * BN + idx]))
            + ((pn[4 * BN + idx] + pn[5 * BN + idx]) + (pn[6 * BN + idx] + pn[7 * BN + idx]))
            + (snf[idx] + snf[BN + idx]);
  float den = ((pd[idx] + pd[BN + idx]) + (pd[2 * BN + idx] + pd[3 * BN + idx]))
            + ((pd[4 * BN + idx] + pd[5 * BN + idx]) + (pd[6 * BN + idx] + pd[7 * BN + idx]))
            + (sdf[idx] + sdf[BN + idx]);
  float4 c = cmg[p];
  float v = fmaf(c.x, vprev[idx], c.y + num) * frcp(c.z + den);
  out[idx] = fmaf(v, ow[p], ob[p]);
  out[BN + idx] = v;
}

extern "C" void kernel_launch(void* const* d_in, const int* in_sizes, int n_in,
                              void* d_out, int out_size, void* d_ws, size_t ws_size,
                              hipStream_t stream) {
  (void)in_sizes; (void)n_in; (void)out_size; (void)ws_size;
  const float* x     = (const float*)d_in[0];
  const float* state = (const float*)d_in[1];
  const float* gleak = (const float*)d_in[2];
  const float* vleak = (const float*)d_in[3];
  const float* cm    = (const float*)d_in[4];
  const float* sigma = (const float*)d_in[5];
  const float* mu    = (const float*)d_in[6];
  const float* w     = (const float*)d_in[7];
  const float* erev  = (const float*)d_in[8];
  const float* ssig  = (const float*)d_in[9];
  const float* smu   = (const float*)d_in[10];
  const float* sw    = (const float*)d_in[11];
  const float* serev = (const float*)d_in[12];
  const float* in_w  = (const float*)d_in[13];
  const float* in_b  = (const float*)d_in[14];
  const float* out_w = (const float*)d_in[15];
  const float* out_b = (const float*)d_in[16];

  float* ws = (float*)d_ws;
  float4* fusedR = (float4*)(ws);                 // 1,048,576 floats
  float4* fusedS = (float4*)(ws + 1048576);       //   524,288
  float4* cmg    = (float4*)(ws + 1572864);       //     2,048
  float*  pnA    = ws + 1574912;                  // 1,048,576  [8][BN]
  float*  pdA    = ws + 2623488;                  // 1,048,576
  float*  pnB    = ws + 3672064;                  // 1,048,576
  float*  pdB    = ws + 4720640;                  // 1,048,576
  float*  snf    = ws + 5769216;                  //   262,144  [2][BN]
  float*  sdf    = ws + 6031360;                  //   262,144
  float*  vA     = ws + 6293504;                  //   131,072
  float*  vB     = ws + 6424576;                  //   131,072  (end 6,555,648 fl = 26.2 MB)

  prep_kernel<<<1536, 256, 0, stream>>>(sigma, mu, w, erev, ssig, smu, sw, serev,
                                        gleak, vleak, cm, fusedR, fusedS, cmg);
  sensory_kernel<<<512, 256, 0, stream>>>(x, in_w, in_b, fusedS, snf, sdf);

  // step 0: partials0(v0=state) -> A
  unfold_kernel<<<1024, 256, 0, stream>>>(fusedR, state, pnA, pdA, snf, sdf, cmg,
                                          vA, pnA, pdA, 1);
  // step 1: v1=f(state,A) -> vA; partials1 -> B
  unfold_kernel<<<1024, 256, 0, stream>>>(fusedR, state, pnA, pdA, snf, sdf, cmg,
                                          vA, pnB, pdB, 0);
  // step 2: v2=f(vA,B) -> vB; partials2 -> A
  unfold_kernel<<<1024, 256, 0, stream>>>(fusedR, vA, pnB, pdB, snf, sdf, cmg,
                                          vB, pnA, pdA, 0);
  // step 3: v3=f(vB,A) -> vA; partials3 -> B
  unfold_kernel<<<1024, 256, 0, stream>>>(fusedR, vB, pnA, pdA, snf, sdf, cmg,
                                          vA, pnB, pdB, 0);
  // step 4: v4=f(vA,B) -> vB; partials4 -> A
  unfold_kernel<<<1024, 256, 0, stream>>>(fusedR, vA, pnB, pdB, snf, sdf, cmg,
                                          vB, pnA, pdA, 0);
  // step 5: v5=f(vB,A) -> vA; partials5 -> B
  unfold_kernel<<<1024, 256, 0, stream>>>(fusedR, vB, pnA, pdA, snf, sdf, cmg,
                                          vA, pnB, pdB, 0);
  // final: v6=f(vA,B) -> out
  final_kernel<<<512, 256, 0, stream>>>(vA, pnB, pdB, snf, sdf, cmg,
                                        out_w, out_b, (float*)d_out);
}

// Round 10
// 165.886 us; speedup vs baseline: 5.7391x; 5.7391x over previous
//
#include <hip/hip_runtime.h>

#define UNITS 512
#define SENSD 256
#define BATCH 256
#define BN (BATCH * UNITS)
#define LOG2E 1.44269504088896340736f
#define CMF (6.0f / 1.001f)   // ODE_UNFOLDS / (ELAPSED_TIME + 0.001)

__device__ __forceinline__ float frcp(float x)  { return __builtin_amdgcn_rcpf(x); }
__device__ __forceinline__ float fexp2(float x) { return __builtin_amdgcn_exp2f(x); }

// Fused params: fusedR/fusedS[pq] = {-sigma*log2e, sigma*mu*log2e, w, w*erev}
// cmg[p] = {cm_t, gleak*vleak, cm_t+gleak+eps, 0}
__global__ __launch_bounds__(256) void prep_kernel(
    const float* __restrict__ sigma, const float* __restrict__ mu,
    const float* __restrict__ w, const float* __restrict__ erev,
    const float* __restrict__ ssig, const float* __restrict__ smu,
    const float* __restrict__ sw, const float* __restrict__ serev,
    const float* __restrict__ gleak, const float* __restrict__ vleak,
    const float* __restrict__ cm,
    float4* __restrict__ fusedR, float4* __restrict__ fusedS,
    float4* __restrict__ cmg) {
  int idx = blockIdx.x * 256 + threadIdx.x;
  if (idx < UNITS * UNITS) {
    float s = sigma[idx], m = mu[idx], ww = w[idx], e = erev[idx];
    fusedR[idx] = make_float4(-s * LOG2E, s * m * LOG2E, ww, ww * e);
  } else {
    int j = idx - UNITS * UNITS;
    if (j < SENSD * UNITS) {
      float s = ssig[j], m = smu[j], ww = sw[j], e = serev[j];
      fusedS[j] = make_float4(-s * LOG2E, s * m * LOG2E, ww, ww * e);
    }
  }
  if (idx < UNITS) {
    float cmt = cm[idx] * CMF, gl = gleak[idx];
    cmg[idx] = make_float4(cmt, gl * vleak[idx], cmt + gl + 1e-8f, 0.f);
  }
}

// Sensory partials over 2 d-chunks of 128 (proven r2 structure, unchanged).
__global__ __launch_bounds__(256) void sensory_kernel(
    const float* __restrict__ x, const float* __restrict__ in_w, const float* __restrict__ in_b,
    const float4* __restrict__ fusedS,
    float* __restrict__ snf, float* __restrict__ sdf) {
  __shared__ float xl[8][128];
  int bi = blockIdx.x;
  int phs = bi & 1, qt = (bi >> 1) & 7, bt = bi >> 4;
  int tid = threadIdx.x;
  for (int i = tid; i < 1024; i += 256) {
    int br = i >> 7, dl = i & 127;
    int d = phs * 128 + dl;
    xl[br][dl] = fmaf(x[(bt * 8 + br) * SENSD + d], in_w[d], in_b[d]);
  }
  __syncthreads();
  int ql = tid & 63, bg = tid >> 6;
  int q = qt * 64 + ql;
  int r0 = bg * 2;
  const float4* F = fusedS + (size_t)(phs * 128) * UNITS + q;
  float n0 = 0.f, dn0 = 0.f, n1 = 0.f, dn1 = 0.f;
  #pragma unroll 8
  for (int dd = 0; dd < 128; ++dd) {
    float4 f = F[(size_t)dd * UNITS];
    float v0 = xl[r0][dd], v1 = xl[r0 + 1][dd];
    float t0 = fexp2(fmaf(f.x, v0, f.y));
    float t1 = fexp2(fmaf(f.x, v1, f.y));
    float s0 = frcp(1.0f + t0);
    float s1 = frcp(1.0f + t1);
    n0 = fmaf(f.w, s0, n0);  dn0 = fmaf(f.z, s0, dn0);
    n1 = fmaf(f.w, s1, n1);  dn1 = fmaf(f.z, s1, dn1);
  }
  int bp0 = (bt * 8 + r0) * UNITS + q;
  size_t o = (size_t)phs * BN + bp0;
  snf[o] = n0;         sdf[o] = dn0;
  snf[o + UNITS] = n1; sdf[o + UNITS] = dn1;
}

// One ODE unfold, 8 batch rows per thread, p-chunk 32, btile 32.
// grid 1024 x 256 thr: bi = ph + 16*(qt + 8*bt); ph<16 (p-chunk 32), qt<8 (q64),
// bt<8 (btile 32). 4 blocks/CU -> 16 waves/CU (proven saturation point).
// Each F float4 serves 8 cells (2 B/cell requested). Plane partials [16][BN].
__global__ __launch_bounds__(256, 4) void unfold_kernel(
    const float4* __restrict__ fusedR, const float* __restrict__ vprev,
    const float* __restrict__ pn_in, const float* __restrict__ pd_in,  // [16][BN]
    const float* __restrict__ snf, const float* __restrict__ sdf,      // [2][BN]
    const float4* __restrict__ cmg,
    float* __restrict__ vout,
    float* __restrict__ pn_out, float* __restrict__ pd_out,            // [16][BN]
    int first) {
  __shared__ float vl[32][40];   // [p-lane][batch-row], pad 40 -> float4-aligned
  int bi = blockIdx.x;
  int ph = bi & 15, qt = (bi >> 4) & 7, bt = bi >> 7;
  int tid = threadIdx.x;
  if (first) {
    for (int i = tid; i < 1024; i += 256) {
      int br = i >> 5, pl = i & 31;
      vl[pl][br] = vprev[(bt * 32 + br) * UNITS + ph * 32 + pl];
    }
  } else {
    for (int i = tid; i < 1024; i += 256) {
      int br = i >> 5, pl = i & 31;
      int p = ph * 32 + pl;
      int bp = (bt * 32 + br) * UNITS + p;
      float num = 0.f, den = 0.f;
      #pragma unroll
      for (int k = 0; k < 16; ++k) {
        num += pn_in[k * BN + bp];
        den += pd_in[k * BN + bp];
      }
      num += snf[bp] + snf[BN + bp];
      den += sdf[bp] + sdf[BN + bp];
      float4 c = cmg[p];
      float v = fmaf(c.x, vprev[bp], c.y + num) * frcp(c.z + den);
      vl[pl][br] = v;
      if (qt == 0) vout[bp] = v;
    }
  }
  __syncthreads();
  int ql = tid & 63, bg = tid >> 6;   // bg < 4
  int q = qt * 64 + ql;
  int r0 = bg * 8;                    // 8 rows per thread
  const float4* F = fusedR + (size_t)(ph * 32) * UNITS + q;
  float n0 = 0.f, n1 = 0.f, n2 = 0.f, n3 = 0.f;
  float n4 = 0.f, n5 = 0.f, n6 = 0.f, n7 = 0.f;
  float d0 = 0.f, d1 = 0.f, d2 = 0.f, d3 = 0.f;
  float d4 = 0.f, d5 = 0.f, d6 = 0.f, d7 = 0.f;
  #pragma unroll 4
  for (int pp = 0; pp < 32; ++pp) {
    float4 f = F[(size_t)pp * UNITS];
    float4 va = *(const float4*)&vl[pp][r0];       // wave-broadcast ds_read_b128
    float4 vb = *(const float4*)&vl[pp][r0 + 4];   // wave-broadcast ds_read_b128
    float t0 = fexp2(fmaf(f.x, va.x, f.y));
    float t1 = fexp2(fmaf(f.x, va.y, f.y));
    float t2 = fexp2(fmaf(f.x, va.z, f.y));
    float t3 = fexp2(fmaf(f.x, va.w, f.y));
    float t4 = fexp2(fmaf(f.x, vb.x, f.y));
    float t5 = fexp2(fmaf(f.x, vb.y, f.y));
    float t6 = fexp2(fmaf(f.x, vb.z, f.y));
    float t7 = fexp2(fmaf(f.x, vb.w, f.y));
    float s0 = frcp(1.0f + t0);
    float s1 = frcp(1.0f + t1);
    float s2 = frcp(1.0f + t2);
    float s3 = frcp(1.0f + t3);
    float s4 = frcp(1.0f + t4);
    float s5 = frcp(1.0f + t5);
    float s6 = frcp(1.0f + t6);
    float s7 = frcp(1.0f + t7);
    n0 = fmaf(f.w, s0, n0);  d0 = fmaf(f.z, s0, d0);
    n1 = fmaf(f.w, s1, n1);  d1 = fmaf(f.z, s1, d1);
    n2 = fmaf(f.w, s2, n2);  d2 = fmaf(f.z, s2, d2);
    n3 = fmaf(f.w, s3, n3);  d3 = fmaf(f.z, s3, d3);
    n4 = fmaf(f.w, s4, n4);  d4 = fmaf(f.z, s4, d4);
    n5 = fmaf(f.w, s5, n5);  d5 = fmaf(f.z, s5, d5);
    n6 = fmaf(f.w, s6, n6);  d6 = fmaf(f.z, s6, d6);
    n7 = fmaf(f.w, s7, n7);  d7 = fmaf(f.z, s7, d7);
  }
  int bp = (bt * 32 + r0) * UNITS + q;
  size_t o = (size_t)ph * BN + bp;
  pn_out[o] = n0;             pd_out[o] = d0;
  pn_out[o + UNITS] = n1;     pd_out[o + UNITS] = d1;
  pn_out[o + 2 * UNITS] = n2; pd_out[o + 2 * UNITS] = d2;
  pn_out[o + 3 * UNITS] = n3; pd_out[o + 3 * UNITS] = d3;
  pn_out[o + 4 * UNITS] = n4; pd_out[o + 4 * UNITS] = d4;
  pn_out[o + 5 * UNITS] = n5; pd_out[o + 5 * UNITS] = d5;
  pn_out[o + 6 * UNITS] = n6; pd_out[o + 6 * UNITS] = d6;
  pn_out[o + 7 * UNITS] = n7; pd_out[o + 7 * UNITS] = d7;
}

// Final combine: v6 from partials_5; write outputs and v_pre.
__global__ __launch_bounds__(256) void final_kernel(
    const float* __restrict__ vprev,
    const float* __restrict__ pn, const float* __restrict__ pd,   // [16][BN]
    const float* __restrict__ snf, const float* __restrict__ sdf, // [2][BN]
    const float4* __restrict__ cmg,
    const float* __restrict__ ow, const float* __restrict__ ob,
    float* __restrict__ out) {
  int idx = blockIdx.x * 256 + threadIdx.x;
  if (idx >= BN) return;
  int p = idx & (UNITS - 1);
  float num = 0.f, den = 0.f;
  #pragma unroll
  for (int k = 0; k < 16; ++k) {
    num += pn[k * BN + idx];
    den += pd[k * BN + idx];
  }
  num += snf[idx] + snf[BN + idx];
  den += sdf[idx] + sdf[BN + idx];
  float4 c = cmg[p];
  float v = fmaf(c.x, vprev[idx], c.y + num) * frcp(c.z + den);
  out[idx] = fmaf(v, ow[p], ob[p]);
  out[BN + idx] = v;
}

extern "C" void kernel_launch(void* const* d_in, const int* in_sizes, int n_in,
                              void* d_out, int out_size, void* d_ws, size_t ws_size,
                              hipStream_t stream) {
  (void)in_sizes; (void)n_in; (void)out_size; (void)ws_size;
  const float* x     = (const float*)d_in[0];
  const float* state = (const float*)d_in[1];
  const float* gleak = (const float*)d_in[2];
  const float* vleak = (const float*)d_in[3];
  const float* cm    = (const float*)d_in[4];
  const float* sigma = (const float*)d_in[5];
  const float* mu    = (const float*)d_in[6];
  const float* w     = (const float*)d_in[7];
  const float* erev  = (const float*)d_in[8];
  const float* ssig  = (const float*)d_in[9];
  const float* smu   = (const float*)d_in[10];
  const float* sw    = (const float*)d_in[11];
  const float* serev = (const float*)d_in[12];
  const float* in_w  = (const float*)d_in[13];
  const float* in_b  = (const float*)d_in[14];
  const float* out_w = (const float*)d_in[15];
  const float* out_b = (const float*)d_in[16];

  float* ws = (float*)d_ws;
  float4* fusedR = (float4*)(ws);                 // 1,048,576 floats
  float4* fusedS = (float4*)(ws + 1048576);       //   524,288
  float4* cmg    = (float4*)(ws + 1572864);       //     2,048
  float*  pnA    = ws + 1574912;                  // 2,097,152  [16][BN]
  float*  pdA    = ws + 3672064;                  // 2,097,152
  float*  pnB    = ws + 5769216;                  // 2,097,152
  float*  pdB    = ws + 7866368;                  // 2,097,152
  float*  snf    = ws + 9963520;                  //   262,144  [2][BN]
  float*  sdf    = ws + 10225664;                 //   262,144
  float*  vA     = ws + 10487808;                 //   131,072
  float*  vB     = ws + 10618880;                 //   131,072  (end 10,749,952 fl = 43.0 MB)

  prep_kernel<<<1536, 256, 0, stream>>>(sigma, mu, w, erev, ssig, smu, sw, serev,
                                        gleak, vleak, cm, fusedR, fusedS, cmg);
  sensory_kernel<<<512, 256, 0, stream>>>(x, in_w, in_b, fusedS, snf, sdf);

  // step 0: partials0(v0=state) -> A
  unfold_kernel<<<1024, 256, 0, stream>>>(fusedR, state, pnA, pdA, snf, sdf, cmg,
                                          vA, pnA, pdA, 1);
  // step 1: v1=f(state,A) -> vA; partials1 -> B
  unfold_kernel<<<1024, 256, 0, stream>>>(fusedR, state, pnA, pdA, snf, sdf, cmg,
                                          vA, pnB, pdB, 0);
  // step 2: v2=f(vA,B) -> vB; partials2 -> A
  unfold_kernel<<<1024, 256, 0, stream>>>(fusedR, vA, pnB, pdB, snf, sdf, cmg,
                                          vB, pnA, pdA, 0);
  // step 3: v3=f(vB,A) -> vA; partials3 -> B
  unfold_kernel<<<1024, 256, 0, stream>>>(fusedR, vB, pnA, pdA, snf, sdf, cmg,
                                          vA, pnB, pdB, 0);
  // step 4: v4=f(vA,B) -> vB; partials4 -> A
  unfold_kernel<<<1024, 256, 0, stream>>>(fusedR, vA, pnB, pdB, snf, sdf, cmg,
                                          vB, pnA, pdA, 0);
  // step 5: v5=f(vB,A) -> vA; partials5 -> B
  unfold_kernel<<<1024, 256, 0, stream>>>(fusedR, vB, pnA, pdA, snf, sdf, cmg,
                                          vA, pnB, pdB, 0);
  // final: v6=f(vA,B) -> out
  final_kernel<<<512, 256, 0, stream>>>(vA, pnB, pdB, snf, sdf, cmg,
                                        out_w, out_b, (float*)d_out);
}

// Round 11
// 159.872 us; speedup vs baseline: 5.9550x; 1.0376x over previous
//
#include <hip/hip_runtime.h>

#define UNITS 512
#define SENSD 256
#define BATCH 256
#define BN (BATCH * UNITS)
#define LOG2E 1.44269504088896340736f
#define CMF (6.0f / 1.001f)   // ODE_UNFOLDS / (ELAPSED_TIME + 0.001)

__device__ __forceinline__ float frcp(float x)  { return __builtin_amdgcn_rcpf(x); }
__device__ __forceinline__ float fexp2(float x) { return __builtin_amdgcn_exp2f(x); }

// Fused params: fusedR/fusedS[pq] = {-sigma*log2e, sigma*mu*log2e, w, w*erev}
// cmg[p] = {cm_t, gleak*vleak, cm_t+gleak+eps, 0}
__global__ __launch_bounds__(256) void prep_kernel(
    const float* __restrict__ sigma, const float* __restrict__ mu,
    const float* __restrict__ w, const float* __restrict__ erev,
    const float* __restrict__ ssig, const float* __restrict__ smu,
    const float* __restrict__ sw, const float* __restrict__ serev,
    const float* __restrict__ gleak, const float* __restrict__ vleak,
    const float* __restrict__ cm,
    float4* __restrict__ fusedR, float4* __restrict__ fusedS,
    float4* __restrict__ cmg) {
  int idx = blockIdx.x * 256 + threadIdx.x;
  if (idx < UNITS * UNITS) {
    float s = sigma[idx], m = mu[idx], ww = w[idx], e = erev[idx];
    fusedR[idx] = make_float4(-s * LOG2E, s * m * LOG2E, ww, ww * e);
  } else {
    int j = idx - UNITS * UNITS;
    if (j < SENSD * UNITS) {
      float s = ssig[j], m = smu[j], ww = sw[j], e = serev[j];
      fusedS[j] = make_float4(-s * LOG2E, s * m * LOG2E, ww, ww * e);
    }
  }
  if (idx < UNITS) {
    float cmt = cm[idx] * CMF, gl = gleak[idx];
    cmg[idx] = make_float4(cmt, gl * vleak[idx], cmt + gl + 1e-8f, 0.f);
  }
}

// Sensory partials over 2 d-chunks of 128 (proven r2 structure, unchanged).
__global__ __launch_bounds__(256) void sensory_kernel(
    const float* __restrict__ x, const float* __restrict__ in_w, const float* __restrict__ in_b,
    const float4* __restrict__ fusedS,
    float* __restrict__ snf, float* __restrict__ sdf) {
  __shared__ float xl[8][128];
  int bi = blockIdx.x;
  int phs = bi & 1, qt = (bi >> 1) & 7, bt = bi >> 4;
  int tid = threadIdx.x;
  for (int i = tid; i < 1024; i += 256) {
    int br = i >> 7, dl = i & 127;
    int d = phs * 128 + dl;
    xl[br][dl] = fmaf(x[(bt * 8 + br) * SENSD + d], in_w[d], in_b[d]);
  }
  __syncthreads();
  int ql = tid & 63, bg = tid >> 6;
  int q = qt * 64 + ql;
  int r0 = bg * 2;
  const float4* F = fusedS + (size_t)(phs * 128) * UNITS + q;
  float n0 = 0.f, dn0 = 0.f, n1 = 0.f, dn1 = 0.f;
  #pragma unroll 8
  for (int dd = 0; dd < 128; ++dd) {
    float4 f = F[(size_t)dd * UNITS];
    float v0 = xl[r0][dd], v1 = xl[r0 + 1][dd];
    float t0 = fexp2(fmaf(f.x, v0, f.y));
    float t1 = fexp2(fmaf(f.x, v1, f.y));
    float s0 = frcp(1.0f + t0);
    float s1 = frcp(1.0f + t1);
    n0 = fmaf(f.w, s0, n0);  dn0 = fmaf(f.z, s0, dn0);
    n1 = fmaf(f.w, s1, n1);  dn1 = fmaf(f.z, s1, dn1);
  }
  int bp0 = (bt * 8 + r0) * UNITS + q;
  size_t o = (size_t)phs * BN + bp0;
  snf[o] = n0;         sdf[o] = dn0;
  snf[o + UNITS] = n1; sdf[o + UNITS] = dn1;
}

// One ODE unfold, 4 batch rows per thread, p-chunk 64, with explicit
// double-buffered register prefetch of the F panel (chunk = 4 rows).
// grid 1024 x 256 thr: bi = ph + 8*(qt + 8*bt); ph<8 (p-chunk 64), qt<8 (q64),
// bt<16 (btile 16). 4 blocks/CU => 16 waves/CU. Prologue reconstructs v_k from
// plane partials [8][BN]; qt==0 blocks persist to vout.
__global__ __launch_bounds__(256, 4) void unfold_kernel(
    const float4* __restrict__ fusedR, const float* __restrict__ vprev,
    const float* __restrict__ pn_in, const float* __restrict__ pd_in,  // [8][BN]
    const float* __restrict__ snf, const float* __restrict__ sdf,      // [2][BN]
    const float4* __restrict__ cmg,
    float* __restrict__ vout,
    float* __restrict__ pn_out, float* __restrict__ pd_out,            // [8][BN]
    int first) {
  __shared__ float vl[64][20];   // [p-lane][batch-row], pad 20 -> 16B-aligned float4 rows
  int bi = blockIdx.x;
  int ph = bi & 7, qt = (bi >> 3) & 7, bt = bi >> 6;
  int tid = threadIdx.x;
  if (first) {
    for (int i = tid; i < 1024; i += 256) {
      int br = i >> 6, pl = i & 63;
      vl[pl][br] = vprev[(bt * 16 + br) * UNITS + ph * 64 + pl];
    }
  } else {
    for (int i = tid; i < 1024; i += 256) {
      int br = i >> 6, pl = i & 63;
      int p = ph * 64 + pl;
      int bp = (bt * 16 + br) * UNITS + p;
      float num = ((pn_in[bp] + pn_in[BN + bp]) + (pn_in[2 * BN + bp] + pn_in[3 * BN + bp]))
                + ((pn_in[4 * BN + bp] + pn_in[5 * BN + bp]) + (pn_in[6 * BN + bp] + pn_in[7 * BN + bp]))
                + (snf[bp] + snf[BN + bp]);
      float den = ((pd_in[bp] + pd_in[BN + bp]) + (pd_in[2 * BN + bp] + pd_in[3 * BN + bp]))
                + ((pd_in[4 * BN + bp] + pd_in[5 * BN + bp]) + (pd_in[6 * BN + bp] + pd_in[7 * BN + bp]))
                + (sdf[bp] + sdf[BN + bp]);
      float4 c = cmg[p];
      float v = fmaf(c.x, vprev[bp], c.y + num) * frcp(c.z + den);
      vl[pl][br] = v;
      if (qt == 0) vout[bp] = v;
    }
  }
  __syncthreads();
  int ql = tid & 63, bg = tid >> 6;   // bg < 4
  int q = qt * 64 + ql;
  int r0 = bg * 4;
  const float4* F = fusedR + (size_t)(ph * 64) * UNITS + q;

  float n0 = 0.f, n1 = 0.f, n2 = 0.f, n3 = 0.f;
  float d0 = 0.f, d1 = 0.f, d2 = 0.f, d3 = 0.f;

  // rolling 4-row register window, prefetched one chunk (4 rows) ahead
  float4 fa[4], fb[4];
  #pragma unroll
  for (int r = 0; r < 4; ++r) fa[r] = F[(size_t)r * UNITS];

  #pragma unroll
  for (int c = 0; c < 16; ++c) {
    // issue next chunk's loads BEFORE computing current chunk (latency hiding)
    if (c < 15) {
      #pragma unroll
      for (int r = 0; r < 4; ++r) fb[r] = F[(size_t)((c + 1) * 4 + r) * UNITS];
    }
    #pragma unroll
    for (int r = 0; r < 4; ++r) {
      float4 f = fa[r];
      float4 vv = *(const float4*)&vl[c * 4 + r][r0];   // wave-broadcast ds_read_b128
      float t0 = fexp2(fmaf(f.x, vv.x, f.y));
      float t1 = fexp2(fmaf(f.x, vv.y, f.y));
      float t2 = fexp2(fmaf(f.x, vv.z, f.y));
      float t3 = fexp2(fmaf(f.x, vv.w, f.y));
      float s0 = frcp(1.0f + t0);
      float s1 = frcp(1.0f + t1);
      float s2 = frcp(1.0f + t2);
      float s3 = frcp(1.0f + t3);
      n0 = fmaf(f.w, s0, n0);  d0 = fmaf(f.z, s0, d0);
      n1 = fmaf(f.w, s1, n1);  d1 = fmaf(f.z, s1, d1);
      n2 = fmaf(f.w, s2, n2);  d2 = fmaf(f.z, s2, d2);
      n3 = fmaf(f.w, s3, n3);  d3 = fmaf(f.z, s3, d3);
    }
    if (c < 15) {
      #pragma unroll
      for (int r = 0; r < 4; ++r) fa[r] = fb[r];
    }
  }

  int bp = (bt * 16 + r0) * UNITS + q;
  size_t o = (size_t)ph * BN + bp;
  pn_out[o] = n0;             pd_out[o] = d0;
  pn_out[o + UNITS] = n1;     pd_out[o + UNITS] = d1;
  pn_out[o + 2 * UNITS] = n2; pd_out[o + 2 * UNITS] = d2;
  pn_out[o + 3 * UNITS] = n3; pd_out[o + 3 * UNITS] = d3;
}

// Final combine: v6 from partials_5; write outputs and v_pre.
__global__ __launch_bounds__(256) void final_kernel(
    const float* __restrict__ vprev,
    const float* __restrict__ pn, const float* __restrict__ pd,   // [8][BN]
    const float* __restrict__ snf, const float* __restrict__ sdf, // [2][BN]
    const float4* __restrict__ cmg,
    const float* __restrict__ ow, const float* __restrict__ ob,
    float* __restrict__ out) {
  int idx = blockIdx.x * 256 + threadIdx.x;
  if (idx >= BN) return;
  int p = idx & (UNITS - 1);
  float num = ((pn[idx] + pn[BN + idx]) + (pn[2 * BN + idx] + pn[3 * BN + idx]))
            + ((pn[4 * BN + idx] + pn[5 * BN + idx]) + (pn[6 * BN + idx] + pn[7 * BN + idx]))
            + (snf[idx] + snf[BN + idx]);
  float den = ((pd[idx] + pd[BN + idx]) + (pd[2 * BN + idx] + pd[3 * BN + idx]))
            + ((pd[4 * BN + idx] + pd[5 * BN + idx]) + (pd[6 * BN + idx] + pd[7 * BN + idx]))
            + (sdf[idx] + sdf[BN + idx]);
  float4 c = cmg[p];
  float v = fmaf(c.x, vprev[idx], c.y + num) * frcp(c.z + den);
  out[idx] = fmaf(v, ow[p], ob[p]);
  out[BN + idx] = v;
}

extern "C" void kernel_launch(void* const* d_in, const int* in_sizes, int n_in,
                              void* d_out, int out_size, void* d_ws, size_t ws_size,
                              hipStream_t stream) {
  (void)in_sizes; (void)n_in; (void)out_size; (void)ws_size;
  const float* x     = (const float*)d_in[0];
  const float* state = (const float*)d_in[1];
  const float* gleak = (const float*)d_in[2];
  const float* vleak = (const float*)d_in[3];
  const float* cm    = (const float*)d_in[4];
  const float* sigma = (const float*)d_in[5];
  const float* mu    = (const float*)d_in[6];
  const float* w     = (const float*)d_in[7];
  const float* erev  = (const float*)d_in[8];
  const float* ssig  = (const float*)d_in[9];
  const float* smu   = (const float*)d_in[10];
  const float* sw    = (const float*)d_in[11];
  const float* serev = (const float*)d_in[12];
  const float* in_w  = (const float*)d_in[13];
  const float* in_b  = (const float*)d_in[14];
  const float* out_w = (const float*)d_in[15];
  const float* out_b = (const float*)d_in[16];

  float* ws = (float*)d_ws;
  float4* fusedR = (float4*)(ws);                 // 1,048,576 floats
  float4* fusedS = (float4*)(ws + 1048576);       //   524,288
  float4* cmg    = (float4*)(ws + 1572864);       //     2,048
  float*  pnA    = ws + 1574912;                  // 1,048,576  [8][BN]
  float*  pdA    = ws + 2623488;                  // 1,048,576
  float*  pnB    = ws + 3672064;                  // 1,048,576
  float*  pdB    = ws + 4720640;                  // 1,048,576
  float*  snf    = ws + 5769216;                  //   262,144  [2][BN]
  float*  sdf    = ws + 6031360;                  //   262,144
  float*  vA     = ws + 6293504;                  //   131,072
  float*  vB     = ws + 6424576;                  //   131,072  (end 6,555,648 fl = 26.2 MB)

  prep_kernel<<<1536, 256, 0, stream>>>(sigma, mu, w, erev, ssig, smu, sw, serev,
                                        gleak, vleak, cm, fusedR, fusedS, cmg);
  sensory_kernel<<<512, 256, 0, stream>>>(x, in_w, in_b, fusedS, snf, sdf);

  // step 0: partials0(v0=state) -> A
  unfold_kernel<<<1024, 256, 0, stream>>>(fusedR, state, pnA, pdA, snf, sdf, cmg,
                                          vA, pnA, pdA, 1);
  // step 1: v1=f(state,A) -> vA; partials1 -> B
  unfold_kernel<<<1024, 256, 0, stream>>>(fusedR, state, pnA, pdA, snf, sdf, cmg,
                                          vA, pnB, pdB, 0);
  // step 2: v2=f(vA,B) -> vB; partials2 -> A
  unfold_kernel<<<1024, 256, 0, stream>>>(fusedR, vA, pnB, pdB, snf, sdf, cmg,
                                          vB, pnA, pdA, 0);
  // step 3: v3=f(vB,A) -> vA; partials3 -> B
  unfold_kernel<<<1024, 256, 0, stream>>>(fusedR, vB, pnA, pdA, snf, sdf, cmg,
                                          vA, pnB, pdB, 0);
  // step 4: v4=f(vA,B) -> vB; partials4 -> A
  unfold_kernel<<<1024, 256, 0, stream>>>(fusedR, vA, pnB, pdB, snf, sdf, cmg,
                                          vB, pnA, pdA, 0);
  // step 5: v5=f(vB,A) -> vA; partials5 -> B
  unfold_kernel<<<1024, 256, 0, stream>>>(fusedR, vB, pnA, pdA, snf, sdf, cmg,
                                          vA, pnB, pdB, 0);
  // final: v6=f(vA,B) -> out
  final_kernel<<<512, 256, 0, stream>>>(vA, pnB, pdB, snf, sdf, cmg,
                                        out_w, out_b, (float*)d_out);
}